// Round 1
// baseline (314.243 us; speedup 1.0000x reference)
//
#include <hip/hip_runtime.h>

#define N_NODES 20000
#define N_EDGES 640000
#define F 128

// ---------------------------------------------------------------------------
// CSR build: count in-degrees, exclusive-scan, fill src lists per dst node.
// ---------------------------------------------------------------------------
__global__ void count_kernel(const int* __restrict__ dst, int* __restrict__ cnt) {
    int e = blockIdx.x * blockDim.x + threadIdx.x;
    if (e < N_EDGES) atomicAdd(&cnt[dst[e]], 1);
}

__global__ void scan_kernel(const int* __restrict__ cnt, int* __restrict__ ptr,
                            int* __restrict__ fill, float* __restrict__ invdeg) {
    // single block, 1024 threads: chunked Hillis-Steele inclusive scan
    __shared__ int sm[1024];
    __shared__ int carry;
    if (threadIdx.x == 0) carry = 0;
    __syncthreads();
    for (int base = 0; base < N_NODES; base += 1024) {
        int i = base + threadIdx.x;
        int v = (i < N_NODES) ? cnt[i] : 0;
        sm[threadIdx.x] = v;
        __syncthreads();
        for (int off = 1; off < 1024; off <<= 1) {
            int t = (threadIdx.x >= off) ? sm[threadIdx.x - off] : 0;
            __syncthreads();
            sm[threadIdx.x] += t;
            __syncthreads();
        }
        int incl = sm[threadIdx.x];
        int excl = incl - v;
        if (i < N_NODES) {
            int p = carry + excl;
            ptr[i]  = p;
            fill[i] = p;
            invdeg[i] = 1.0f / fmaxf((float)v, 1.0f);
        }
        __syncthreads();
        if (threadIdx.x == 1023) carry += sm[1023];
        __syncthreads();
    }
    if (threadIdx.x == 0) ptr[N_NODES] = carry;
}

__global__ void fill_kernel(const int* __restrict__ src, const int* __restrict__ dst,
                            int* __restrict__ fill, int* __restrict__ csr_src) {
    int e = blockIdx.x * blockDim.x + threadIdx.x;
    if (e < N_EDGES) {
        int d = dst[e];
        int pos = atomicAdd(&fill[d], 1);
        csr_src[pos] = src[e];
    }
}

// ---------------------------------------------------------------------------
// Mean aggregation: one wave (64 lanes) per node; each lane owns 2 features
// (float2). Edge indices loaded coalesced 64-at-a-time, broadcast via shfl.
// ---------------------------------------------------------------------------
__global__ void agg_kernel(const float* __restrict__ feat, const int* __restrict__ ptr,
                           const int* __restrict__ csr_src, const float* __restrict__ invdeg,
                           float* __restrict__ out) {
    int gwave = (blockIdx.x * blockDim.x + threadIdx.x) >> 6;
    int lane  = threadIdx.x & 63;
    if (gwave >= N_NODES) return;
    int beg = ptr[gwave], end = ptr[gwave + 1];
    float accx = 0.f, accy = 0.f;
    const float2* feat2 = (const float2*)feat;
    for (int base = beg; base < end; base += 64) {
        int m = end - base; if (m > 64) m = 64;
        int myidx = (lane < m) ? csr_src[base + lane] : 0;
        for (int j = 0; j < m; ++j) {
            int s = __shfl(myidx, j);
            float2 v = feat2[(size_t)s * 64 + lane];
            accx += v.x; accy += v.y;
        }
    }
    float sc = invdeg[gwave];
    float2 o; o.x = accx * sc; o.y = accy * sc;
    ((float2*)out)[(size_t)gwave * 64 + lane] = o;
}

// ---------------------------------------------------------------------------
// C[M x 128] = relu(A[M x 128] @ W[128 x 128] + b).  Block: 256 threads,
// 32 rows x 128 cols; per-thread 4x4 micro-tile. A staged in LDS (+1 pad
// word kills the stride-128 8-way bank conflict); W via L1/L2.
// ---------------------------------------------------------------------------
__global__ void gemm_relu_kernel(const float* __restrict__ A, const float* __restrict__ W,
                                 const float* __restrict__ b, float* __restrict__ C) {
    __shared__ float As[32][F + 1];
    int tid  = threadIdx.x;
    int row0 = blockIdx.x * 32;

    const float4* A4 = (const float4*)(A + (size_t)row0 * F);
    for (int i = tid; i < 32 * 32; i += 256) {   // 32 rows x 32 float4
        float4 v = A4[i];
        int r = i >> 5, c4 = (i & 31) * 4;
        As[r][c4] = v.x; As[r][c4 + 1] = v.y; As[r][c4 + 2] = v.z; As[r][c4 + 3] = v.w;
    }
    __syncthreads();

    int tx = tid & 31;   // col group: cols 4*tx .. 4*tx+3
    int ty = tid >> 5;   // row group: rows 4*ty .. 4*ty+3
    int c0 = tx * 4;
    int r0 = ty * 4;
    float acc[4][4] = {};

    for (int k = 0; k < F; ++k) {
        float4 w = *(const float4*)(W + k * F + c0);
        float a[4];
#pragma unroll
        for (int i = 0; i < 4; ++i) a[i] = As[r0 + i][k];
#pragma unroll
        for (int i = 0; i < 4; ++i) {
            acc[i][0] += a[i] * w.x;
            acc[i][1] += a[i] * w.y;
            acc[i][2] += a[i] * w.z;
            acc[i][3] += a[i] * w.w;
        }
    }

    float4 bias = *(const float4*)(b + c0);
#pragma unroll
    for (int i = 0; i < 4; ++i) {
        int r = row0 + r0 + i;
        float4 o;
        o.x = fmaxf(acc[i][0] + bias.x, 0.f);
        o.y = fmaxf(acc[i][1] + bias.y, 0.f);
        o.z = fmaxf(acc[i][2] + bias.z, 0.f);
        o.w = fmaxf(acc[i][3] + bias.w, 0.f);
        *(float4*)(C + (size_t)r * F + c0) = o;
    }
}

// ---------------------------------------------------------------------------
// out[N x 2] = h[N x 128] @ W3[128 x 2] + b3. One wave per node, shuffle
// reduce. No relu.
// ---------------------------------------------------------------------------
__global__ void final_kernel(const float* __restrict__ h, const float* __restrict__ W3,
                             const float* __restrict__ b3, float* __restrict__ out) {
    int gwave = (blockIdx.x * blockDim.x + threadIdx.x) >> 6;
    int lane  = threadIdx.x & 63;
    if (gwave >= N_NODES) return;
    float2 v = ((const float2*)h)[(size_t)gwave * 64 + lane];   // h[., 2*lane], h[., 2*lane+1]
    float4 w = ((const float4*)W3)[lane];                       // W3[2l][0],W3[2l][1],W3[2l+1][0],W3[2l+1][1]
    float a0 = v.x * w.x + v.y * w.z;
    float a1 = v.x * w.y + v.y * w.w;
#pragma unroll
    for (int off = 32; off > 0; off >>= 1) {
        a0 += __shfl_down(a0, off);
        a1 += __shfl_down(a1, off);
    }
    if (lane == 0) {
        out[(size_t)gwave * 2]     = a0 + b3[0];
        out[(size_t)gwave * 2 + 1] = a1 + b3[1];
    }
}

// ---------------------------------------------------------------------------
extern "C" void kernel_launch(void* const* d_in, const int* in_sizes, int n_in,
                              void* d_out, int out_size, void* d_ws, size_t ws_size,
                              hipStream_t stream) {
    const float* x   = (const float*)d_in[0];
    const int*   ei  = (const int*)d_in[1];
    const int*   src = ei;
    const int*   dst = ei + N_EDGES;
    const float* W1 = (const float*)d_in[2];
    const float* b1 = (const float*)d_in[3];
    const float* W2 = (const float*)d_in[4];
    const float* b2 = (const float*)d_in[5];
    const float* W3 = (const float*)d_in[6];
    const float* b3 = (const float*)d_in[7];
    float* out = (float*)d_out;

    // workspace carve-out (256B-aligned chunks)
    char* base = (char*)d_ws;
    size_t off = 0;
    auto take = [&](size_t bytes) -> char* {
        char* p = base + off;
        off += (bytes + 255) & ~(size_t)255;
        return p;
    };
    int*   cnt    = (int*)  take(N_NODES * sizeof(int));
    int*   ptr    = (int*)  take((N_NODES + 1) * sizeof(int));
    int*   fill   = (int*)  take(N_NODES * sizeof(int));
    float* invdeg = (float*)take(N_NODES * sizeof(float));
    int*   csr    = (int*)  take(N_EDGES * sizeof(int));
    float* aggr   = (float*)take((size_t)N_NODES * F * sizeof(float));
    float* h      = (float*)take((size_t)N_NODES * F * sizeof(float));

    hipMemsetAsync(cnt, 0, N_NODES * sizeof(int), stream);

    count_kernel<<<(N_EDGES + 255) / 256, 256, 0, stream>>>(dst, cnt);
    scan_kernel<<<1, 1024, 0, stream>>>(cnt, ptr, fill, invdeg);
    fill_kernel<<<(N_EDGES + 255) / 256, 256, 0, stream>>>(src, dst, fill, csr);

    // layer 1
    agg_kernel<<<(N_NODES * 64 + 255) / 256, 256, 0, stream>>>(x, ptr, csr, invdeg, aggr);
    gemm_relu_kernel<<<N_NODES / 32, 256, 0, stream>>>(aggr, W1, b1, h);
    // layer 2
    agg_kernel<<<(N_NODES * 64 + 255) / 256, 256, 0, stream>>>(h, ptr, csr, invdeg, aggr);
    gemm_relu_kernel<<<N_NODES / 32, 256, 0, stream>>>(aggr, W2, b2, h);
    // output projection
    final_kernel<<<(N_NODES * 64 + 255) / 256, 256, 0, stream>>>(h, W3, b3, out);
}